// Round 1
// baseline (509.869 us; speedup 1.0000x reference)
//
#include <hip/hip_runtime.h>
#include <hip/hip_bf16.h>

#define NU 262144
#define GG 128
#define PG 134          // padded field side (128 + 2*3)
#define DD 128

typedef __attribute__((ext_vector_type(8))) short short8;   // 8 bf16 (4 VGPR) MFMA frag
typedef __attribute__((ext_vector_type(4))) float f32x4;
typedef __attribute__((ext_vector_type(4))) int int4v;

// fp32 -> bf16, round-to-nearest-even
__device__ __forceinline__ unsigned short f2b(float f) {
  union { float f; unsigned u; } v; v.f = f;
  unsigned r = v.u + 0x7fffu + ((v.u >> 16) & 1u);
  return (unsigned short)(r >> 16);
}

__device__ __forceinline__ float fast_tanh(float x) {
  float ax = fabsf(x);
  float e  = __expf(ax + ax);
  float t  = 1.0f - __fdividef(2.0f, e + 1.0f);
  return copysignf(t, x);
}

// neighborhood offset -> flat delta in padded 134^3 field
struct alignas(16) DoffT { int v[128]; };
static constexpr DoffT mkdoff() {
  DoffT t{};
  for (int d = 0; d < 128; ++d) {
    int i = d / 49, r = d % 49, j = r / 7, k = r % 7;
    t.v[d] = ((i - 3) * PG + (j - 3)) * PG + (k - 3);
  }
  return t;
}
__device__ constexpr DoffT DOFF = mkdoff();

// ---------------- prep 1: clamped pad + bf16 convert of the field ----------------
__global__ void prep_field(const float* __restrict__ f, unsigned short* __restrict__ fp) {
  int idx = blockIdx.x * 256 + threadIdx.x;
  if (idx >= PG * PG * PG) return;
  int z = idx % PG, t = idx / PG;
  int y = t % PG, x = t / PG;
  int xx = min(max(x - 3, 0), GG - 1);
  int yy = min(max(y - 3, 0), GG - 1);
  int zz = min(max(z - 3, 0), GG - 1);
  fp[idx] = f2b(f[(xx * GG + yy) * GG + zz]);
}

// ---------------- prep 2: W1/W2 -> frag-major bf16 (arg0 layout: outer=n, k-chunks by lane>>4) ----
__global__ void prep_w(const float* __restrict__ W1, const float* __restrict__ W2,
                       unsigned short* __restrict__ w1t, unsigned short* __restrict__ w2t) {
  int idx = blockIdx.x * 256 + threadIdx.x;   // one 16B frag-chunk per thread
  if (idx < 4096) {                            // W1: 8 kt * 8 nt * 64 lanes
    int kt = idx >> 9, nt = (idx >> 6) & 7, ln = idx & 63;
    int n = nt * 16 + (ln & 15), k0 = kt * 32 + (ln >> 4) * 8;
    short8 s;
#pragma unroll
    for (int j = 0; j < 8; ++j) s[j] = (short)f2b(W1[(k0 + j) * DD + n]);
    ((short8*)w1t)[idx] = s;
  } else if (idx < 6144) {                     // W2: 4 kt * 8 nt * 64 lanes
    int c = idx - 4096;
    int kt = c >> 9, nt = (c >> 6) & 7, ln = c & 63;
    int n = nt * 16 + (ln & 15), k0 = kt * 32 + (ln >> 4) * 8;
    short8 s;
#pragma unroll
    for (int j = 0; j < 8; ++j) s[j] = (short)f2b(W2[(k0 + j) * DD + n]);
    ((short8*)w2t)[c] = s;
  }
}

// ---------------- main kernel: 4 waves * 64 units per block ----------------
__global__ __launch_bounds__(256, 2) void atu_main(
    const float* __restrict__ pos, const float* __restrict__ sig,
    const float* __restrict__ offs, const float* __restrict__ b1,
    const float* __restrict__ b2, const unsigned short* __restrict__ fpad,
    const short8* __restrict__ w1f, const short8* __restrict__ w2f,
    float* __restrict__ out_stab, float* __restrict__ out_pos)
{
  __shared__ unsigned short hs[4][8192];     // 16KB per wave, 64KB total
  const int tid  = threadIdx.x;
  const int wid  = tid >> 6, lane = tid & 63;
  const int lg   = lane >> 4, lm = lane & 15;
  const int ubase = blockIdx.x * 256 + wid * 64;
  char* hsb = (char*)&hs[wid][0];

  float ssqe[2];

#pragma unroll
  for (int ev = 0; ev < 2; ++ev) {
    // ---- per-unit-tile gather bases (padded coords, no clamps needed later) ----
    int abase[4];
#pragma unroll
    for (int ut = 0; ut < 4; ++ut) {
      int u = ubase + ut * 16 + lm;
      float px = pos[u * 3 + 0], py = pos[u * 3 + 1], pz = pos[u * 3 + 2];
      if (ev) { px += offs[u * 3 + 0]; py += offs[u * 3 + 1]; pz += offs[u * 3 + 2]; }
      int pcx = min(max((int)px, 0), GG - 1);
      int pcy = min(max((int)py, 0), GG - 1);
      int pcz = min(max((int)pz, 0), GG - 1);
      abase[ut] = ((pcx + 3) * PG + (pcy + 3)) * PG + (pcz + 3);
    }

    // ---- GEMM1: hT[128 feat][64 units] += W1t x combinedT ----
    f32x4 acc[8][4];
#pragma unroll
    for (int nt = 0; nt < 8; ++nt)
#pragma unroll
      for (int ut = 0; ut < 4; ++ut) acc[nt][ut] = f32x4{0.f, 0.f, 0.f, 0.f};

    for (int kt = 0; kt < 4; ++kt) {          // signature half (k = 0..127)
      short8 bfr[4];
#pragma unroll
      for (int ut = 0; ut < 4; ++ut) {
        int u = ubase + ut * 16 + lm;
        const f32x4* sp = (const f32x4*)(sig + (u * DD + kt * 32 + lg * 8));
        f32x4 s0 = sp[0], s1 = sp[1];
        short8 fr;
        fr[0] = (short)f2b(s0[0]); fr[1] = (short)f2b(s0[1]);
        fr[2] = (short)f2b(s0[2]); fr[3] = (short)f2b(s0[3]);
        fr[4] = (short)f2b(s1[0]); fr[5] = (short)f2b(s1[1]);
        fr[6] = (short)f2b(s1[2]); fr[7] = (short)f2b(s1[3]);
        bfr[ut] = fr;
      }
#pragma unroll
      for (int nt = 0; nt < 8; ++nt) {
        short8 af = w1f[(kt * 8 + nt) * 64 + lane];
#pragma unroll
        for (int ut = 0; ut < 4; ++ut)
          acc[nt][ut] = __builtin_amdgcn_mfma_f32_16x16x32_bf16(af, bfr[ut], acc[nt][ut], 0, 0, 0);
      }
    }

    for (int kt = 4; kt < 8; ++kt) {          // gathered-local half (k = 128..255)
      int d0 = (kt - 4) * 32 + lg * 8;
      int4v dv0 = *(const int4v*)&DOFF.v[d0];
      int4v dv1 = *(const int4v*)&DOFF.v[d0 + 4];
      short8 bfr[4];
#pragma unroll
      for (int ut = 0; ut < 4; ++ut) {
        int ab = abase[ut];
        short8 fr;
        fr[0] = (short)fpad[ab + dv0[0]]; fr[1] = (short)fpad[ab + dv0[1]];
        fr[2] = (short)fpad[ab + dv0[2]]; fr[3] = (short)fpad[ab + dv0[3]];
        fr[4] = (short)fpad[ab + dv1[0]]; fr[5] = (short)fpad[ab + dv1[1]];
        fr[6] = (short)fpad[ab + dv1[2]]; fr[7] = (short)fpad[ab + dv1[3]];
        bfr[ut] = fr;
      }
#pragma unroll
      for (int nt = 0; nt < 8; ++nt) {
        short8 af = w1f[(kt * 8 + nt) * 64 + lane];
#pragma unroll
        for (int ut = 0; ut < 4; ++ut)
          acc[nt][ut] = __builtin_amdgcn_mfma_f32_16x16x32_bf16(af, bfr[ut], acc[nt][ut], 0, 0, 0);
      }
    }

    // ---- bias + tanh + write h to swizzled per-wave LDS (transpose) ----
#pragma unroll
    for (int nt = 0; nt < 8; ++nt) {
      f32x4 b1v = *(const f32x4*)(b1 + nt * 16 + lg * 4);
#pragma unroll
      for (int ut = 0; ut < 4; ++ut) {
        int u = ut * 16 + lm;
        float h0 = fast_tanh(acc[nt][ut][0] + b1v[0]);
        float h1 = fast_tanh(acc[nt][ut][1] + b1v[1]);
        float h2 = fast_tanh(acc[nt][ut][2] + b1v[2]);
        float h3 = fast_tanh(acc[nt][ut][3] + b1v[3]);
        unsigned q0 = (unsigned)f2b(h0) | ((unsigned)f2b(h1) << 16);
        unsigned q1 = (unsigned)f2b(h2) | ((unsigned)f2b(h3) << 16);
        int byte = (u * 256 + nt * 32 + lg * 8) ^ ((u & 7) << 4);
        *(unsigned long long*)(hsb + byte) =
            (unsigned long long)q0 | ((unsigned long long)q1 << 32);
      }
    }

    // ---- GEMM2: respT[128 feat][64 units] = W2t x hT ----
    f32x4 acc2[8][4];
#pragma unroll
    for (int nt = 0; nt < 8; ++nt)
#pragma unroll
      for (int ut = 0; ut < 4; ++ut) acc2[nt][ut] = f32x4{0.f, 0.f, 0.f, 0.f};

    for (int kt = 0; kt < 4; ++kt) {
      short8 hfr[4];
#pragma unroll
      for (int ut = 0; ut < 4; ++ut) {
        int u = ut * 16 + lm;
        int byte = (u * 256 + kt * 64 + lg * 16) ^ ((u & 7) << 4);
        hfr[ut] = *(const short8*)(hsb + byte);
      }
#pragma unroll
      for (int nt = 0; nt < 8; ++nt) {
        short8 af = w2f[(kt * 8 + nt) * 64 + lane];
#pragma unroll
        for (int ut = 0; ut < 4; ++ut)
          acc2[nt][ut] = __builtin_amdgcn_mfma_f32_16x16x32_bf16(af, hfr[ut], acc2[nt][ut], 0, 0, 0);
      }
    }

    // ---- || resp - sig ||^2 ----
    float ssq[4] = {0.f, 0.f, 0.f, 0.f};
#pragma unroll
    for (int nt = 0; nt < 8; ++nt) {
      f32x4 b2v = *(const f32x4*)(b2 + nt * 16 + lg * 4);
#pragma unroll
      for (int ut = 0; ut < 4; ++ut) {
        int u = ubase + ut * 16 + lm;
        f32x4 sv = *(const f32x4*)(sig + (u * DD + nt * 16 + lg * 4));
#pragma unroll
        for (int r = 0; r < 4; ++r) {
          float d = acc2[nt][ut][r] + b2v[r] - sv[r];
          ssq[ut] = fmaf(d, d, ssq[ut]);
        }
      }
    }
#pragma unroll
    for (int ut = 0; ut < 4; ++ut) {
      ssq[ut] += __shfl_xor(ssq[ut], 16, 64);
      ssq[ut] += __shfl_xor(ssq[ut], 32, 64);
    }
    ssqe[ev] = (lg == 0) ? ssq[0] : (lg == 1) ? ssq[1] : (lg == 2) ? ssq[2] : ssq[3];
  }

  // ---- accept / outputs: lane l owns unit ubase + l ----
  int ul = ubase + lane;
  float px = pos[ul * 3 + 0], py = pos[ul * 3 + 1], pz = pos[ul * 3 + 2];
  float ox = offs[ul * 3 + 0], oy = offs[ul * 3 + 1], oz = offs[ul * 3 + 2];
  bool ok = ssqe[1] <= ssqe[0];
  out_stab[ul] = sqrtf(ok ? ssqe[1] : ssqe[0]);
  out_pos[ul * 3 + 0] = ok ? px + ox : px;
  out_pos[ul * 3 + 1] = ok ? py + oy : py;
  out_pos[ul * 3 + 2] = ok ? pz + oz : pz;
}

extern "C" void kernel_launch(void* const* d_in, const int* in_sizes, int n_in,
                              void* d_out, int out_size, void* d_ws, size_t ws_size,
                              hipStream_t stream) {
  const float* field = (const float*)d_in[0];
  const float* pos   = (const float*)d_in[1];
  const float* sig   = (const float*)d_in[2];
  const float* offs  = (const float*)d_in[3];
  const float* W1    = (const float*)d_in[4];
  const float* b1    = (const float*)d_in[5];
  const float* W2    = (const float*)d_in[6];
  const float* b2    = (const float*)d_in[7];
  float* out_stab = (float*)d_out;
  float* out_pos  = out_stab + NU;

  char* ws = (char*)d_ws;
  // ws layout: [0, 4812208) padded bf16 field; then frag-major weights
  unsigned short* fpad = (unsigned short*)ws;
  unsigned short* w1t  = (unsigned short*)(ws + 4812800);
  unsigned short* w2t  = (unsigned short*)(ws + 4878336);

  prep_field<<<(PG * PG * PG + 255) / 256, 256, 0, stream>>>(field, fpad);
  prep_w<<<24, 256, 0, stream>>>(W1, W2, w1t, w2t);
  atu_main<<<NU / 256, 256, 0, stream>>>(pos, sig, offs, b1, b2, fpad,
                                         (const short8*)w1t, (const short8*)w2t,
                                         out_stab, out_pos);
}